// Round 4
// baseline (186.472 us; speedup 1.0000x reference)
//
#include <hip/hip_runtime.h>
#include <hip/hip_bf16.h>

// f32 in / f32 out; bf16 MFMA inside (2% relative threshold; absmax r3 = 3.9e-3).
// Round-4: (1) GRID 512->1024 => 4 blocks/CU resident (was 2) for latency hiding;
// (2) pre-pass converts z to bf16 in d_ws (25.6 MB) => gather bytes halve, L2
// footprint 51->25.6 MB. Fallback to f32-z path if ws_size too small.

#define N_NODES 100000
#define N_EDGES 500000
#define D_IN    128
#define D_HID   256
#define M_TILE  32
#define NTILES  (N_EDGES / M_TILE)   // 15625 exactly
#define LDS_STRIDE 136               // 128 + 8 bf16 pad
#define GRID    1024                 // 4 blocks/CU resident

typedef __bf16 bf16x8 __attribute__((ext_vector_type(8)));
typedef float  f32x4  __attribute__((ext_vector_type(4)));
typedef float  f32x2  __attribute__((ext_vector_type(2)));

union F4H { float4 v; f32x2 h[2]; };

__device__ __forceinline__ unsigned int pkbf(f32x2 q) {
    union { __hip_bfloat162 b; unsigned int u; } c;
    c.b = __float22bfloat162_rn(make_float2(q.x, q.y));   // RNE packed cvt
    return c.u;
}
__device__ __forceinline__ float bflo(unsigned int w) {
    union { unsigned int u; float f; } c; c.u = w << 16; return c.f;
}
__device__ __forceinline__ float bfhi(unsigned int w) {
    union { unsigned int u; float f; } c; c.u = w & 0xffff0000u; return c.f;
}

// mish(x) = x * N/(N+2), N = E*(E+2), E = e^x — exact identity, float2-vectorized
__device__ __forceinline__ f32x2 mish2(f32x2 x) {
    f32x2 xc = {fminf(x.x, 20.0f), fminf(x.y, 20.0f)};
    f32x2 E  = {__expf(xc.x), __expf(xc.y)};
    f32x2 num = E * (E + 2.0f);
    f32x2 den = num + 2.0f;
    f32x2 r  = {__builtin_amdgcn_rcpf(den.x), __builtin_amdgcn_rcpf(den.y)};
    return x * num * r;
}

// ---- pre-pass: z (f32, 12.8M elems) -> bf16 in ws. 6250 blocks x 256 thr x 8 ----
__global__ __launch_bounds__(256)
void z_to_bf16(const float* __restrict__ z, ushort* __restrict__ zb) {
    const int i = (blockIdx.x * 256 + threadIdx.x) * 8;   // exact cover: 6250*256*8
    F4H a{*reinterpret_cast<const float4*>(z + i)};
    F4H b{*reinterpret_cast<const float4*>(z + i + 4)};
    *reinterpret_cast<uint4*>(zb + i) =
        make_uint4(pkbf(a.h[0]), pkbf(a.h[1]), pkbf(b.h[0]), pkbf(b.h[1]));
}

template<bool ZBF>
__global__ __launch_bounds__(512, 4)
void edge_decoder_kernel(const float*  __restrict__ zf,
                         const ushort* __restrict__ zb,
                         const int*    __restrict__ edge,
                         const float*  __restrict__ W1,
                         const float*  __restrict__ b1,
                         const float*  __restrict__ W2,
                         const float*  __restrict__ b2,
                         float*        __restrict__ out) {
    __shared__ ushort xbuf[2][M_TILE * LDS_STRIDE];
    __shared__ float  lpart[2][8][M_TILE];

    const int t    = threadIdx.x;
    const int wave = t >> 6;
    const int lane = t & 63;
    const int quad = lane >> 4;
    const int nlo  = lane & 15;

    // ---- W1 -> bf16 B-fragments (wave owns hidden cols [32w, 32w+32)) ----
    bf16x8 bfrag[4][2];
    float  b1f[2], w2f[2];
    #pragma unroll
    for (int nt = 0; nt < 2; ++nt) {
        const int n = wave * 32 + nt * 16 + nlo;
        const float* wrow = W1 + n * D_IN;
        #pragma unroll
        for (int ks = 0; ks < 4; ++ks) {
            F4H w0{*reinterpret_cast<const float4*>(wrow + ks * 32 + quad * 8)};
            F4H w1{*reinterpret_cast<const float4*>(wrow + ks * 32 + quad * 8 + 4)};
            union { unsigned int u[4]; bf16x8 v; } o;
            o.u[0] = pkbf(w0.h[0]); o.u[1] = pkbf(w0.h[1]);
            o.u[2] = pkbf(w1.h[0]); o.u[3] = pkbf(w1.h[1]);
            bfrag[ks][nt] = o.v;
        }
        b1f[nt] = b1[n];
        w2f[nt] = W2[n];
    }
    const float b2f = b2[0];

    const int s_slot = t >> 4;   // edge slot 0..31
    const int cch    = t & 15;   // 8-elem column chunk

    // ---- pipeline prologue ----
    int tile = blockIdx.x;
    uint4  ua, va;                 // bf16-z in-flight rows
    float4 a0, a1, c0, c1;         // f32-z in-flight rows
    {
        const int e = tile * M_TILE + s_slot;
        const int u = edge[e], v = edge[N_EDGES + e];
        if constexpr (ZBF) {
            ua = *reinterpret_cast<const uint4*>(zb + (size_t)u * D_IN + cch * 8);
            va = *reinterpret_cast<const uint4*>(zb + (size_t)v * D_IN + cch * 8);
        } else {
            const float* zu = zf + (size_t)u * D_IN + cch * 8;
            const float* zv = zf + (size_t)v * D_IN + cch * 8;
            a0 = *reinterpret_cast<const float4*>(zu);
            a1 = *reinterpret_cast<const float4*>(zu + 4);
            c0 = *reinterpret_cast<const float4*>(zv);
            c1 = *reinterpret_cast<const float4*>(zv + 4);
        }
    }
    int u_n, v_n;
    {
        const int t1 = min(tile + GRID, NTILES - 1);
        const int e1 = t1 * M_TILE + s_slot;
        u_n = edge[e1]; v_n = edge[N_EDGES + e1];
    }

    int  p = 0;
    bool have_prev = false;
    int  prev_base = 0;

    for (; tile < NTILES; tile += GRID) {
        // ---- A: convert current tile's rows -> xbuf[p] ----
        if constexpr (ZBF) {
            unsigned int uu[4] = {ua.x, ua.y, ua.z, ua.w};
            unsigned int vv[4] = {va.x, va.y, va.z, va.w};
            unsigned int r[4];
            #pragma unroll
            for (int j = 0; j < 4; ++j) {
                f32x2 fu = {bflo(uu[j]), bfhi(uu[j])};
                f32x2 fv = {bflo(vv[j]), bfhi(vv[j])};
                r[j] = pkbf(fu * fv);
            }
            *reinterpret_cast<uint4*>(&xbuf[p][s_slot * LDS_STRIDE + cch * 8]) =
                make_uint4(r[0], r[1], r[2], r[3]);
        } else {
            F4H A0{a0}, A1{a1}, C0{c0}, C1{c1};
            *reinterpret_cast<uint4*>(&xbuf[p][s_slot * LDS_STRIDE + cch * 8]) =
                make_uint4(pkbf(A0.h[0] * C0.h[0]), pkbf(A0.h[1] * C0.h[1]),
                           pkbf(A1.h[0] * C1.h[0]), pkbf(A1.h[1] * C1.h[1]));
        }
        // ---- B: the single barrier ----
        __syncthreads();

        // ---- C: issue next tile's z loads + edge indices 2 tiles ahead ----
        if constexpr (ZBF) {
            ua = *reinterpret_cast<const uint4*>(zb + (size_t)u_n * D_IN + cch * 8);
            va = *reinterpret_cast<const uint4*>(zb + (size_t)v_n * D_IN + cch * 8);
        } else {
            const float* zu = zf + (size_t)u_n * D_IN + cch * 8;
            const float* zv = zf + (size_t)v_n * D_IN + cch * 8;
            a0 = *reinterpret_cast<const float4*>(zu);
            a1 = *reinterpret_cast<const float4*>(zu + 4);
            c0 = *reinterpret_cast<const float4*>(zv);
            c1 = *reinterpret_cast<const float4*>(zv + 4);
        }
        {
            const int t2 = min(tile + 2 * GRID, NTILES - 1);
            const int e2 = t2 * M_TILE + s_slot;
            u_n = edge[e2]; v_n = edge[N_EDGES + e2];
        }

        // ---- E: combine + store PREVIOUS tile ----
        if (have_prev && t < M_TILE) {
            const int pp = p ^ 1;
            float logit = b2f;
            #pragma unroll
            for (int w = 0; w < 8; ++w) logit += lpart[pp][w][t];
            out[prev_base + t] = __builtin_amdgcn_rcpf(1.0f + __expf(-logit));
        }

        // ---- D: MFMA + epilogue -> lpart[p] ----
        f32x4 acc[2][2];
        #pragma unroll
        for (int mt = 0; mt < 2; ++mt)
            #pragma unroll
            for (int nt = 0; nt < 2; ++nt)
                acc[mt][nt] = (f32x4){0.f, 0.f, 0.f, 0.f};

        #pragma unroll
        for (int ks = 0; ks < 4; ++ks) {
            bf16x8 af[2];
            #pragma unroll
            for (int mt = 0; mt < 2; ++mt)
                af[mt] = *reinterpret_cast<const bf16x8*>(
                    &xbuf[p][(mt * 16 + nlo) * LDS_STRIDE + ks * 32 + quad * 8]);
            #pragma unroll
            for (int mt = 0; mt < 2; ++mt)
                #pragma unroll
                for (int nt = 0; nt < 2; ++nt)
                    acc[mt][nt] = __builtin_amdgcn_mfma_f32_16x16x32_bf16(
                        af[mt], bfrag[ks][nt], acc[mt][nt], 0, 0, 0);
        }

        // D layout: row = mt*16 + quad*4 + r, col = nlo + 16nt (+32*wave)
        #pragma unroll
        for (int mt = 0; mt < 2; ++mt) {
            #pragma unroll
            for (int pr = 0; pr < 2; ++pr) {
                f32x2 s2 = {0.f, 0.f};
                #pragma unroll
                for (int nt = 0; nt < 2; ++nt) {
                    f32x2 h = {acc[mt][nt][2 * pr]     + b1f[nt],
                               acc[mt][nt][2 * pr + 1] + b1f[nt]};
                    f32x2 m = mish2(h);
                    s2.x += m.x * w2f[nt];
                    s2.y += m.y * w2f[nt];
                }
                float sx = s2.x, sy = s2.y;
                sx += __shfl_xor(sx, 1); sy += __shfl_xor(sy, 1);
                sx += __shfl_xor(sx, 2); sy += __shfl_xor(sy, 2);
                sx += __shfl_xor(sx, 4); sy += __shfl_xor(sy, 4);
                sx += __shfl_xor(sx, 8); sy += __shfl_xor(sy, 8);
                if (nlo == 0) {
                    const int row = mt * 16 + quad * 4 + pr * 2;
                    lpart[p][wave][row]     = sx;
                    lpart[p][wave][row + 1] = sy;
                }
            }
        }

        have_prev = true;
        prev_base = tile * M_TILE;
        p ^= 1;
    }

    // ---- drain ----
    __syncthreads();
    if (have_prev && t < M_TILE) {
        const int pp = p ^ 1;
        float logit = b2f;
        #pragma unroll
        for (int w = 0; w < 8; ++w) logit += lpart[pp][w][t];
        out[prev_base + t] = __builtin_amdgcn_rcpf(1.0f + __expf(-logit));
    }
}

extern "C" void kernel_launch(void* const* d_in, const int* in_sizes, int n_in,
                              void* d_out, int out_size, void* d_ws, size_t ws_size,
                              hipStream_t stream) {
    const float* z    = (const float*)d_in[0];
    const int*   edge = (const int*)d_in[1];
    const float* W1   = (const float*)d_in[2];
    const float* b1   = (const float*)d_in[3];
    const float* W2   = (const float*)d_in[4];
    const float* b2   = (const float*)d_in[5];
    float* out = (float*)d_out;

    const size_t zb_bytes = (size_t)N_NODES * D_IN * sizeof(ushort);  // 25.6 MB
    if (ws_size >= zb_bytes) {
        ushort* zb = (ushort*)d_ws;
        z_to_bf16<<<dim3((N_NODES * D_IN) / (256 * 8)), dim3(256), 0, stream>>>(z, zb);
        edge_decoder_kernel<true><<<dim3(GRID), dim3(512), 0, stream>>>(
            z, zb, edge, W1, b1, W2, b2, out);
    } else {
        edge_decoder_kernel<false><<<dim3(GRID), dim3(512), 0, stream>>>(
            z, nullptr, edge, W1, b1, W2, b2, out);
    }
}